// Round 5
// baseline (677.748 us; speedup 1.0000x reference)
//
#include <hip/hip_runtime.h>
#include <math.h>

#define NEG_SLOPE 0.2f
#define BN_EPS 1e-5f
#define SCAN_T 1024

typedef short short8 __attribute__((ext_vector_type(8)));
typedef float float4v __attribute__((ext_vector_type(4)));

// float -> bf16 bits, round-to-nearest-even
static __device__ inline unsigned short f2bf(float f) {
    unsigned u = __float_as_uint(f);
    u = u + 0x7fffu + ((u >> 16) & 1u);
    return (unsigned short)(u >> 16);
}

static __device__ inline void unpack8(uint4 v, float* f) {
    f[0] = __uint_as_float(v.x << 16);
    f[1] = __uint_as_float(v.x & 0xffff0000u);
    f[2] = __uint_as_float(v.y << 16);
    f[3] = __uint_as_float(v.y & 0xffff0000u);
    f[4] = __uint_as_float(v.z << 16);
    f[5] = __uint_as_float(v.z & 0xffff0000u);
    f[6] = __uint_as_float(v.w << 16);
    f[7] = __uint_as_float(v.w & 0xffff0000u);
}

static __device__ inline void unpack4(uint2 v, float* f) {
    f[0] = __uint_as_float(v.x << 16);
    f[1] = __uint_as_float(v.x & 0xffff0000u);
    f[2] = __uint_as_float(v.y << 16);
    f[3] = __uint_as_float(v.y & 0xffff0000u);
}

// ---------------------------------------------------------------------------
// CSR build
// ---------------------------------------------------------------------------
__global__ __launch_bounds__(256) void zero_k(int* __restrict__ p, int n) {
    int i = blockIdx.x * blockDim.x + threadIdx.x;
    if (i < n) p[i] = 0;
}

__global__ __launch_bounds__(256) void hist_k(const int* __restrict__ dst,
                                              int E, int Etot, int* __restrict__ deg) {
    int i = blockIdx.x * blockDim.x + threadIdx.x;
    if (i >= Etot) return;
    int d = (i < E) ? dst[i] : (i - E);
    atomicAdd(&deg[d], 1);
}

// exclusive scan; also zeroes cnt for the following scatter
__global__ __launch_bounds__(SCAN_T) void scan_k(const int* __restrict__ deg,
                                                 int* __restrict__ rowptr,
                                                 int* __restrict__ cnt, int N) {
    __shared__ int sums[SCAN_T];
    int t = threadIdx.x;
    int chunk = (N + SCAN_T - 1) / SCAN_T;
    int lo = t * chunk;
    int hi = lo + chunk; if (hi > N) hi = N;
    int s = 0;
    for (int i = lo; i < hi; i++) s += deg[i];
    sums[t] = s;
    __syncthreads();
    for (int off = 1; off < SCAN_T; off <<= 1) {
        int v = (t >= off) ? sums[t - off] : 0;
        __syncthreads();
        sums[t] += v;
        __syncthreads();
    }
    int base = (t > 0) ? sums[t - 1] : 0;
    for (int i = lo; i < hi; i++) { rowptr[i] = base; base += deg[i]; cnt[i] = 0; }
    if (t == SCAN_T - 1) rowptr[N] = sums[SCAN_T - 1];
}

__global__ __launch_bounds__(256) void scatter_k(const int* __restrict__ src,
                                                 const int* __restrict__ dst,
                                                 int E, int Etot,
                                                 const int* __restrict__ rowptr,
                                                 int* __restrict__ cnt,
                                                 int* __restrict__ esrc) {
    int i = blockIdx.x * blockDim.x + threadIdx.x;
    if (i >= Etot) return;
    int d = (i < E) ? dst[i] : (i - E);
    int s = (i < E) ? src[i] : (i - E);
    int pos = rowptr[d] + atomicAdd(&cnt[d], 1);
    esrc[pos] = s;
}

// ---------------------------------------------------------------------------
// Weight packing: [p0|p1|p2] -> MFMA B-fragment-major bf16.
// out[((kt*ntiles+nt)*64 + quad*16+nr)*8 + j] = B[kt*32+quad*8+j][nt*16+nr]
// ---------------------------------------------------------------------------
static __device__ inline void pack_one(int idx,
                                       const float* p0, const float* p1,
                                       const float* p2,
                                       int w0, int w1, int w2,
                                       int Ksrc, int Ncat,
                                       unsigned short* out) {
    int k = idx / Ncat, n = idx - k * Ncat;
    float v = 0.f;
    if (k < Ksrc) {
        if (n < w0) v = p0[(size_t)k * w0 + n];
        else if (n < w0 + w1) v = p1[(size_t)k * w1 + (n - w0)];
        else if (w2 > 0 && n < w0 + w1 + w2) v = p2[(size_t)k * w2 + (n - w0 - w1)];
    }
    int kt = k >> 5, kr = k & 31;
    int quad = kr >> 3, j = kr & 7;
    int nt = n >> 4, nr = n & 15;
    int ntiles = Ncat >> 4;
    out[((size_t)(kt * ntiles + nt) * 64 + quad * 16 + nr) * 8 + j] = f2bf(v);
}

__global__ __launch_bounds__(256) void pack_all(const float* __restrict__ w1s,
                                                const float* __restrict__ w1d,
                                                const float* __restrict__ r0w,
                                                const float* __restrict__ w2s,
                                                const float* __restrict__ w2d,
                                                const float* __restrict__ w3s,
                                                const float* __restrict__ w3d,
                                                const float* __restrict__ r2w,
                                                unsigned short* __restrict__ Wb1,
                                                unsigned short* __restrict__ Wb2,
                                                unsigned short* __restrict__ Wb3) {
    const int S1 = 128 * 384, S2 = 128 * 256, S3 = 128 * 144;
    int idx = blockIdx.x * blockDim.x + threadIdx.x;
    if (idx < S1) pack_one(idx, w1s, w1d, r0w, 128, 128, 128, 100, 384, Wb1);
    else if (idx < S1 + S2) pack_one(idx - S1, w2s, w2d, nullptr, 128, 128, 0, 128, 256, Wb2);
    else if (idx < S1 + S2 + S3) pack_one(idx - S1 - S2, w3s, w3d, r2w, 47, 47, 47, 128, 144, Wb3);
}

// convert fp32 [N,Ksrc] -> bf16 [N,Kpad] (zero-padded)
__global__ __launch_bounds__(256) void conv_bf(const float* __restrict__ x,
                                               unsigned short* __restrict__ out,
                                               int N, int Ksrc, int Kpad) {
    int idx = blockIdx.x * blockDim.x + threadIdx.x;
    if (idx >= N * Kpad) return;
    int n = idx / Kpad, k = idx - n * Kpad;
    out[idx] = f2bf(k < Ksrc ? x[(size_t)n * Ksrc + k] : 0.f);
}

// ---------------------------------------------------------------------------
// MFMA bf16 GEMM: one wave = 16 x (16*NT) tile.
// cols < res_off -> bf16 into XLR (col >= bf_remap shifted by +bf_shift);
// cols in [res_off, ncat_valid) -> fp32 into RES; cols >= ncat_valid dropped.
// ---------------------------------------------------------------------------
template <int NT>
__global__ __launch_bounds__(256) void mfma_gemm(const unsigned short* __restrict__ A,
                                                 const unsigned short* __restrict__ Bp,
                                                 unsigned short* __restrict__ XLR,
                                                 float* __restrict__ RES,
                                                 int M, int Kpad, int Ncat,
                                                 int ncat_valid, int res_off,
                                                 int bf_remap, int bf_shift,
                                                 int bf_stride, int res_stride) {
    int wid = (blockIdx.x * blockDim.x + threadIdx.x) >> 6;
    int lane = threadIdx.x & 63;
    int ngroups = Ncat / (16 * NT);
    int mtiles = M >> 4;
    int mt = wid / ngroups;
    int ng = wid - mt * ngroups;
    if (mt >= mtiles) return;
    int quad = lane >> 4;
    int nr = lane & 15;
    int row = mt * 16 + nr;
    int ntiles = Ncat >> 4;

    float4v acc[NT];
#pragma unroll
    for (int t = 0; t < NT; t++) acc[t] = (float4v){0.f, 0.f, 0.f, 0.f};

    for (int k0 = 0; k0 < Kpad; k0 += 32) {
        short8 a = *(const short8*)(A + (size_t)row * Kpad + k0 + quad * 8);
        int kt = k0 >> 5;
        const unsigned short* bbase =
            Bp + ((size_t)(kt * ntiles + ng * NT) * 64 + lane) * 8;
#pragma unroll
        for (int t = 0; t < NT; t++) {
            short8 b = *(const short8*)(bbase + (size_t)t * 64 * 8);
            acc[t] = __builtin_amdgcn_mfma_f32_16x16x32_bf16(a, b, acc[t], 0, 0, 0);
        }
    }
    int rowb = mt * 16 + quad * 4;
#pragma unroll
    for (int t = 0; t < NT; t++) {
        int col = (ng * NT + t) * 16 + nr;
        if (col >= ncat_valid) continue;
        if (col < res_off) {
            int bc = (col >= bf_remap) ? col + bf_shift : col;
#pragma unroll
            for (int r = 0; r < 4; r++)
                XLR[(size_t)(rowb + r) * bf_stride + bc] = f2bf(acc[t][r]);
        } else {
            int rc = col - res_off;
#pragma unroll
            for (int r = 0; r < 4; r++)
                RES[(size_t)(rowb + r) * res_stride + rc] = acc[t][r];
        }
    }
}

// ---------------------------------------------------------------------------
// Fused GATv2 agg + epilogue, H=4 C=32. One wave per dst node.
// 16-lane edge groups (4 edges in flight); lane gl owns channels gl*8..+7
// (head = gl/4). XLR rows of 256 bf16: xl @0..127, xr @128..255.
// mode 1: h = relu(BN(agg + bias + RES + resB)) -> hout fp32 + hbf bf16
// mode 2: h = relu(BN(agg + bias + hprev))      -> hbf bf16
// ---------------------------------------------------------------------------
__global__ __launch_bounds__(256) void gat_agg4_fused(
    const int* __restrict__ rowptr, const int* __restrict__ esrc,
    const unsigned short* __restrict__ xlr, const float* __restrict__ att,
    const float* __restrict__ RES, const float* __restrict__ resB,
    const float* __restrict__ hprev, const float* __restrict__ bias,
    const float* __restrict__ g, const float* __restrict__ bb,
    const float* __restrict__ mm, const float* __restrict__ vv,
    float* __restrict__ hout, unsigned short* __restrict__ hbf,
    int N, int mode) {
    int d = blockIdx.x * 4 + (threadIdx.x >> 6);
    if (d >= N) return;
    int lane = threadIdx.x & 63;
    int gl = lane & 15, grp = lane >> 4;

    float xr[8], at[8];
    {
        uint4 xv = *(const uint4*)(xlr + (size_t)d * 256 + 128 + gl * 8);
        unpack8(xv, xr);
        float4 a0 = *(const float4*)(att + gl * 8);
        float4 a1 = *(const float4*)(att + gl * 8 + 4);
        at[0] = a0.x; at[1] = a0.y; at[2] = a0.z; at[3] = a0.w;
        at[4] = a1.x; at[5] = a1.y; at[6] = a1.z; at[7] = a1.w;
    }
    int beg = rowptr[d], end = rowptr[d + 1];
    float den = 0.f;
    float acc[8] = {0.f, 0.f, 0.f, 0.f, 0.f, 0.f, 0.f, 0.f};
    for (int j = beg + grp; j < end; j += 4) {
        int s = esrc[j];
        uint4 xv = *(const uint4*)(xlr + (size_t)s * 256 + gl * 8);
        float xf[8];
        unpack8(xv, xf);
        float t = 0.f;
#pragma unroll
        for (int k = 0; k < 8; k++) {
            float v = xf[k] + xr[k];
            v = v > 0.f ? v : NEG_SLOPE * v;
            t = fmaf(v, at[k], t);
        }
        t += __shfl_xor(t, 1);   // head-quad reduce (lanes gl&~3 .. +3)
        t += __shfl_xor(t, 2);
        float p = __expf(t);
        den += p;
#pragma unroll
        for (int k = 0; k < 8; k++) acc[k] = fmaf(p, xf[k], acc[k]);
    }
    // combine the 4 edge groups
    den += __shfl_xor(den, 16);
    den += __shfl_xor(den, 32);
#pragma unroll
    for (int k = 0; k < 8; k++) {
        acc[k] += __shfl_xor(acc[k], 16);
        acc[k] += __shfl_xor(acc[k], 32);
    }
    if (grp == 0) {
        float inv = 1.f / den;
        int c0 = gl * 8;
        unsigned short pk[8];
#pragma unroll
        for (int k = 0; k < 8; k++) {
            int c = c0 + k;
            float o = acc[k] * inv + bias[c];
            if (mode == 1) o += RES[(size_t)d * 128 + c] + resB[c];
            else           o += hprev[(size_t)d * 128 + c];
            o = (o - mm[c]) * rsqrtf(vv[c] + BN_EPS) * g[c] + bb[c];
            o = fmaxf(o, 0.f);
            if (mode == 1) hout[(size_t)d * 128 + c] = o;
            pk[k] = f2bf(o);
        }
        uint4 w;
        w.x = (unsigned)pk[0] | ((unsigned)pk[1] << 16);
        w.y = (unsigned)pk[2] | ((unsigned)pk[3] << 16);
        w.z = (unsigned)pk[4] | ((unsigned)pk[5] << 16);
        w.w = (unsigned)pk[6] | ((unsigned)pk[7] << 16);
        *(uint4*)(hbf + (size_t)d * 128 + c0) = w;
    }
}

// ---------------------------------------------------------------------------
// Fused GATv2 agg + epilogue, H=1 C=47 (layer 3). One wave per dst node.
// 16-lane edge groups; lane gl owns channels gl*4..+3 (pad ch masked by att=0).
// XLR rows of 128 bf16: xl @0..47(pad), xr @64..111(pad).
// out = BN(agg + b3 + RES + res2_b), no relu.
// ---------------------------------------------------------------------------
__global__ __launch_bounds__(256) void gat_agg1_fused(
    const int* __restrict__ rowptr, const int* __restrict__ esrc,
    const unsigned short* __restrict__ xlr, const float* __restrict__ att,
    const float* __restrict__ RES, const float* __restrict__ resB,
    const float* __restrict__ bias,
    const float* __restrict__ g, const float* __restrict__ bb,
    const float* __restrict__ mm, const float* __restrict__ vv,
    float* __restrict__ out, int N) {
    int d = blockIdx.x * 4 + (threadIdx.x >> 6);
    if (d >= N) return;
    int lane = threadIdx.x & 63;
    int gl = lane & 15, grp = lane >> 4;

    float xr[4], at[4];
    {
        uint2 xv = *(const uint2*)(xlr + (size_t)d * 128 + 64 + gl * 4);
        unpack4(xv, xr);
#pragma unroll
        for (int k = 0; k < 4; k++) {
            int c = gl * 4 + k;
            at[k] = (c < 47) ? att[c] : 0.f;
        }
    }
    int beg = rowptr[d], end = rowptr[d + 1];
    float den = 0.f;
    float acc[4] = {0.f, 0.f, 0.f, 0.f};
    for (int j = beg + grp; j < end; j += 4) {
        int s = esrc[j];
        uint2 xv = *(const uint2*)(xlr + (size_t)s * 128 + gl * 4);
        float xf[4];
        unpack4(xv, xf);
        float t = 0.f;
#pragma unroll
        for (int k = 0; k < 4; k++) {
            float v = xf[k] + xr[k];
            v = v > 0.f ? v : NEG_SLOPE * v;
            t = fmaf(v, at[k], t);
        }
        t += __shfl_xor(t, 1);   // 16-lane group reduce
        t += __shfl_xor(t, 2);
        t += __shfl_xor(t, 4);
        t += __shfl_xor(t, 8);
        float p = __expf(t);
        den += p;
#pragma unroll
        for (int k = 0; k < 4; k++) acc[k] = fmaf(p, xf[k], acc[k]);
    }
    den += __shfl_xor(den, 16);
    den += __shfl_xor(den, 32);
#pragma unroll
    for (int k = 0; k < 4; k++) {
        acc[k] += __shfl_xor(acc[k], 16);
        acc[k] += __shfl_xor(acc[k], 32);
    }
    if (grp == 0 && gl < 12) {
        float inv = 1.f / den;
#pragma unroll
        for (int k = 0; k < 4; k++) {
            int c = gl * 4 + k;
            if (c < 47) {
                float o = acc[k] * inv + bias[c] + RES[(size_t)d * 48 + c] + resB[c];
                o = (o - mm[c]) * rsqrtf(vv[c] + BN_EPS) * g[c] + bb[c];
                out[(size_t)d * 47 + c] = o;
            }
        }
    }
}

// ---------------------------------------------------------------------------
extern "C" void kernel_launch(void* const* d_in, const int* in_sizes, int n_in,
                              void* d_out, int out_size, void* d_ws, size_t ws_size,
                              hipStream_t stream) {
    const float* x      = (const float*)d_in[0];
    const int*   ei     = (const int*)d_in[1];
    const float* w1_src = (const float*)d_in[2];
    const float* w1_dst = (const float*)d_in[3];
    const float* att1   = (const float*)d_in[4];
    const float* b1     = (const float*)d_in[5];
    const float* bn1_g  = (const float*)d_in[6];
    const float* bn1_b  = (const float*)d_in[7];
    const float* bn1_m  = (const float*)d_in[8];
    const float* bn1_v  = (const float*)d_in[9];
    const float* res0_w = (const float*)d_in[10];
    const float* res0_b = (const float*)d_in[11];
    const float* w2_src = (const float*)d_in[12];
    const float* w2_dst = (const float*)d_in[13];
    const float* att2   = (const float*)d_in[14];
    const float* b2     = (const float*)d_in[15];
    const float* bn2_g  = (const float*)d_in[16];
    const float* bn2_b  = (const float*)d_in[17];
    const float* bn2_m  = (const float*)d_in[18];
    const float* bn2_v  = (const float*)d_in[19];
    const float* w3_src = (const float*)d_in[20];
    const float* w3_dst = (const float*)d_in[21];
    const float* att3   = (const float*)d_in[22];
    const float* b3     = (const float*)d_in[23];
    const float* bn3_g  = (const float*)d_in[24];
    const float* bn3_b  = (const float*)d_in[25];
    const float* bn3_m  = (const float*)d_in[26];
    const float* bn3_v  = (const float*)d_in[27];
    const float* res2_w = (const float*)d_in[28];
    const float* res2_b = (const float*)d_in[29];

    const int F_IN = 100, W1 = 128;
    const int KP = 128;
    const int NC1 = 384, NC2 = 256, NC3 = 144;
    int N = in_sizes[0] / F_IN;
    int E = in_sizes[1] / 2;
    int Etot = E + N;
    const int* src = ei;
    const int* dst = ei + E;

    // ---- workspace layout (float units) ----
    float* ws = (float*)d_ws;
    size_t o = 0;
    unsigned short* XLR = (unsigned short*)(ws + o); o += (size_t)N * 128;  // [N,256] bf16
    float* B_res = ws + o; o += (size_t)N * 128;   // residual cols fp32
    float* B_h   = ws + o; o += (size_t)N * 128;   // layer-1 h fp32
    unsigned short* A_bf = (unsigned short*)(ws + o); o += (size_t)N * 64;  // [N,128] bf16
    unsigned short* Wb1  = (unsigned short*)(ws + o); o += (size_t)KP * NC1 / 2;
    unsigned short* Wb2  = (unsigned short*)(ws + o); o += (size_t)KP * NC2 / 2;
    unsigned short* Wb3  = (unsigned short*)(ws + o); o += (size_t)KP * NC3 / 2;
    int* I_deg    = (int*)(ws + o); o += N;
    int* I_cnt    = (int*)(ws + o); o += N;
    int* I_rowptr = (int*)(ws + o); o += N + 4;
    int* I_esrc   = (int*)(ws + o); o += Etot;
    (void)ws_size; (void)n_in; (void)out_size;

    // ---- CSR build ----
    zero_k<<<(N + 255) / 256, 256, 0, stream>>>(I_deg, N);
    hist_k<<<(Etot + 255) / 256, 256, 0, stream>>>(dst, E, Etot, I_deg);
    scan_k<<<1, SCAN_T, 0, stream>>>(I_deg, I_rowptr, I_cnt, N);
    scatter_k<<<(Etot + 255) / 256, 256, 0, stream>>>(src, dst, E, Etot, I_rowptr,
                                                      I_cnt, I_esrc);

    // ---- weight packing (single launch) ----
    {
        int tot = KP * (NC1 + NC2 + NC3);
        pack_all<<<(tot + 255) / 256, 256, 0, stream>>>(
            w1_src, w1_dst, res0_w, w2_src, w2_dst, w3_src, w3_dst, res2_w,
            Wb1, Wb2, Wb3);
    }

    int aggGrid = (N + 3) / 4;
    int mtiles = (N + 15) / 16;

    // ---------------- layer 1 ----------------
    conv_bf<<<(N * KP + 255) / 256, 256, 0, stream>>>(x, A_bf, N, F_IN, KP);
    {
        int waves = mtiles * (NC1 / 64);
        mfma_gemm<4><<<(waves * 64 + 255) / 256, 256, 0, stream>>>(
            A_bf, Wb1, XLR, B_res, N, KP, NC1, 384, 256, 384, 0, 256, 128);
    }
    gat_agg4_fused<<<aggGrid, 256, 0, stream>>>(
        I_rowptr, I_esrc, XLR, att1, B_res, res0_b, nullptr, b1,
        bn1_g, bn1_b, bn1_m, bn1_v, B_h, A_bf, N, 1);

    // ---------------- layer 2 ----------------
    {
        int waves = mtiles * (NC2 / 64);
        mfma_gemm<4><<<(waves * 64 + 255) / 256, 256, 0, stream>>>(
            A_bf, Wb2, XLR, B_res, N, KP, NC2, 256, 256, 256, 0, 256, 128);
    }
    gat_agg4_fused<<<aggGrid, 256, 0, stream>>>(
        I_rowptr, I_esrc, XLR, att2, nullptr, nullptr, B_h, b2,
        bn2_g, bn2_b, bn2_m, bn2_v, nullptr, A_bf, N, 2);

    // ---------------- layer 3 ----------------
    {
        int waves = mtiles * (NC3 / 48);
        mfma_gemm<3><<<(waves * 64 + 255) / 256, 256, 0, stream>>>(
            A_bf, Wb3, XLR, B_res, N, KP, NC3, 141, 94, 47, 17, 128, 48);
    }
    gat_agg1_fused<<<aggGrid, 256, 0, stream>>>(
        I_rowptr, I_esrc, XLR, att3, B_res, res2_b, b3,
        bn3_g, bn3_b, bn3_m, bn3_v, (float*)d_out, N);
}

// Round 6
// 553.437 us; speedup vs baseline: 1.2246x; 1.2246x over previous
//
#include <hip/hip_runtime.h>
#include <math.h>

#define NEG_SLOPE 0.2f
#define BN_EPS 1e-5f
#define SCAN_T 1024

typedef short short8 __attribute__((ext_vector_type(8)));
typedef float float4v __attribute__((ext_vector_type(4)));

// float -> bf16 bits, round-to-nearest-even
static __device__ inline unsigned short f2bf(float f) {
    unsigned u = __float_as_uint(f);
    u = u + 0x7fffu + ((u >> 16) & 1u);
    return (unsigned short)(u >> 16);
}
static __device__ inline float lo16(unsigned v) { return __uint_as_float(v << 16); }
static __device__ inline float hi16(unsigned v) { return __uint_as_float(v & 0xffff0000u); }

static __device__ inline void unpack4(uint2 v, float* f) {
    f[0] = lo16(v.x); f[1] = hi16(v.x);
    f[2] = lo16(v.y); f[3] = hi16(v.y);
}

// ---------------------------------------------------------------------------
// CSR build
// ---------------------------------------------------------------------------
__global__ __launch_bounds__(256) void zero_k(int* __restrict__ p, int n) {
    int i = blockIdx.x * blockDim.x + threadIdx.x;
    if (i < n) p[i] = 0;
}

__global__ __launch_bounds__(256) void hist_k(const int* __restrict__ dst,
                                              int E, int Etot, int* __restrict__ deg) {
    int i = blockIdx.x * blockDim.x + threadIdx.x;
    if (i >= Etot) return;
    int d = (i < E) ? dst[i] : (i - E);
    atomicAdd(&deg[d], 1);
}

// exclusive scan; also zeroes cnt for the following scatter
__global__ __launch_bounds__(SCAN_T) void scan_k(const int* __restrict__ deg,
                                                 int* __restrict__ rowptr,
                                                 int* __restrict__ cnt, int N) {
    __shared__ int sums[SCAN_T];
    int t = threadIdx.x;
    int chunk = (N + SCAN_T - 1) / SCAN_T;
    int lo = t * chunk;
    int hi = lo + chunk; if (hi > N) hi = N;
    int s = 0;
    for (int i = lo; i < hi; i++) s += deg[i];
    sums[t] = s;
    __syncthreads();
    for (int off = 1; off < SCAN_T; off <<= 1) {
        int v = (t >= off) ? sums[t - off] : 0;
        __syncthreads();
        sums[t] += v;
        __syncthreads();
    }
    int base = (t > 0) ? sums[t - 1] : 0;
    for (int i = lo; i < hi; i++) { rowptr[i] = base; base += deg[i]; cnt[i] = 0; }
    if (t == SCAN_T - 1) rowptr[N] = sums[SCAN_T - 1];
}

__global__ __launch_bounds__(256) void scatter_k(const int* __restrict__ src,
                                                 const int* __restrict__ dst,
                                                 int E, int Etot,
                                                 const int* __restrict__ rowptr,
                                                 int* __restrict__ cnt,
                                                 int* __restrict__ esrc) {
    int i = blockIdx.x * blockDim.x + threadIdx.x;
    if (i >= Etot) return;
    int d = (i < E) ? dst[i] : (i - E);
    int s = (i < E) ? src[i] : (i - E);
    int pos = rowptr[d] + atomicAdd(&cnt[d], 1);
    esrc[pos] = s;
}

// ---------------------------------------------------------------------------
// Weight packing: [p0|p1|p2] -> MFMA B-fragment-major bf16.
// ---------------------------------------------------------------------------
static __device__ inline void pack_one(int idx,
                                       const float* p0, const float* p1,
                                       const float* p2,
                                       int w0, int w1, int w2,
                                       int Ksrc, int Ncat,
                                       unsigned short* out) {
    int k = idx / Ncat, n = idx - k * Ncat;
    float v = 0.f;
    if (k < Ksrc) {
        if (n < w0) v = p0[(size_t)k * w0 + n];
        else if (n < w0 + w1) v = p1[(size_t)k * w1 + (n - w0)];
        else if (w2 > 0 && n < w0 + w1 + w2) v = p2[(size_t)k * w2 + (n - w0 - w1)];
    }
    int kt = k >> 5, kr = k & 31;
    int quad = kr >> 3, j = kr & 7;
    int nt = n >> 4, nr = n & 15;
    int ntiles = Ncat >> 4;
    out[((size_t)(kt * ntiles + nt) * 64 + quad * 16 + nr) * 8 + j] = f2bf(v);
}

__global__ __launch_bounds__(256) void pack_all(const float* __restrict__ w1s,
                                                const float* __restrict__ w1d,
                                                const float* __restrict__ r0w,
                                                const float* __restrict__ w2s,
                                                const float* __restrict__ w2d,
                                                const float* __restrict__ w3s,
                                                const float* __restrict__ w3d,
                                                const float* __restrict__ r2w,
                                                unsigned short* __restrict__ Wb1,
                                                unsigned short* __restrict__ Wb2,
                                                unsigned short* __restrict__ Wb3) {
    const int S1 = 128 * 384, S2 = 128 * 256, S3 = 128 * 144;
    int idx = blockIdx.x * blockDim.x + threadIdx.x;
    if (idx < S1) pack_one(idx, w1s, w1d, r0w, 128, 128, 128, 100, 384, Wb1);
    else if (idx < S1 + S2) pack_one(idx - S1, w2s, w2d, nullptr, 128, 128, 0, 128, 256, Wb2);
    else if (idx < S1 + S2 + S3) pack_one(idx - S1 - S2, w3s, w3d, r2w, 47, 47, 47, 128, 144, Wb3);
}

// convert fp32 [N,Ksrc] -> bf16 [N,Kpad] (zero-padded)
__global__ __launch_bounds__(256) void conv_bf(const float* __restrict__ x,
                                               unsigned short* __restrict__ out,
                                               int N, int Ksrc, int Kpad) {
    int idx = blockIdx.x * blockDim.x + threadIdx.x;
    if (idx >= N * Kpad) return;
    int n = idx / Kpad, k = idx - n * Kpad;
    out[idx] = f2bf(k < Ksrc ? x[(size_t)n * Ksrc + k] : 0.f);
}

// ---------------------------------------------------------------------------
// MFMA bf16 GEMM: one wave = 16 x (16*NT) tile.
// cols < res_off -> bf16 into XLR (col >= bf_remap shifted by +bf_shift);
// cols in [res_off, ncat_valid) -> fp32 into RES; cols >= ncat_valid dropped.
// ---------------------------------------------------------------------------
template <int NT>
__global__ __launch_bounds__(256) void mfma_gemm(const unsigned short* __restrict__ A,
                                                 const unsigned short* __restrict__ Bp,
                                                 unsigned short* __restrict__ XLR,
                                                 float* __restrict__ RES,
                                                 int M, int Kpad, int Ncat,
                                                 int ncat_valid, int res_off,
                                                 int bf_remap, int bf_shift,
                                                 int bf_stride, int res_stride) {
    int wid = (blockIdx.x * blockDim.x + threadIdx.x) >> 6;
    int lane = threadIdx.x & 63;
    int ngroups = Ncat / (16 * NT);
    int mtiles = M >> 4;
    int mt = wid / ngroups;
    int ng = wid - mt * ngroups;
    if (mt >= mtiles) return;
    int quad = lane >> 4;
    int nr = lane & 15;
    int row = mt * 16 + nr;
    int ntiles = Ncat >> 4;

    float4v acc[NT];
#pragma unroll
    for (int t = 0; t < NT; t++) acc[t] = (float4v){0.f, 0.f, 0.f, 0.f};

    for (int k0 = 0; k0 < Kpad; k0 += 32) {
        short8 a = *(const short8*)(A + (size_t)row * Kpad + k0 + quad * 8);
        int kt = k0 >> 5;
        const unsigned short* bbase =
            Bp + ((size_t)(kt * ntiles + ng * NT) * 64 + lane) * 8;
#pragma unroll
        for (int t = 0; t < NT; t++) {
            short8 b = *(const short8*)(bbase + (size_t)t * 64 * 8);
            acc[t] = __builtin_amdgcn_mfma_f32_16x16x32_bf16(a, b, acc[t], 0, 0, 0);
        }
    }
    int rowb = mt * 16 + quad * 4;
#pragma unroll
    for (int t = 0; t < NT; t++) {
        int col = (ng * NT + t) * 16 + nr;
        if (col >= ncat_valid) continue;
        if (col < res_off) {
            int bc = (col >= bf_remap) ? col + bf_shift : col;
#pragma unroll
            for (int r = 0; r < 4; r++)
                XLR[(size_t)(rowb + r) * bf_stride + bc] = f2bf(acc[t][r]);
        } else {
            int rc = col - res_off;
#pragma unroll
            for (int r = 0; r < 4; r++)
                RES[(size_t)(rowb + r) * res_stride + rc] = acc[t][r];
        }
    }
}

// ---------------------------------------------------------------------------
// Fused GATv2 agg + epilogue, H=4 C=32. One wave per dst node.
// Round-4 memory shape: one edge per wave-iteration; lane owns channels
// (2*lane, 2*lane+1) -> one dword gather/lane = one contiguous 256B row per
// wave-load; explicit unroll-4 keeps 4 rows in flight. 4-shfl head reduce.
// XLR rows of 256 bf16: xl @0..127, xr @128..255.
// mode 1: h = relu(BN(agg + bias + RES + resB))      -> hbf (bf16)
// mode 2: h = relu(BN(agg + bias + bf16(hbf_prev)))  -> hbf in-place
// ---------------------------------------------------------------------------
__global__ __launch_bounds__(256) void gat_agg4_fused(
    const int* __restrict__ rowptr, const int* __restrict__ esrc,
    const unsigned short* __restrict__ xlr, const float* __restrict__ att,
    const float* __restrict__ RES, const float* __restrict__ resB,
    const float* __restrict__ bias,
    const float* __restrict__ g, const float* __restrict__ bb,
    const float* __restrict__ mm, const float* __restrict__ vv,
    unsigned short* __restrict__ hbf, int N, int mode) {
    int d = blockIdx.x * 4 + (threadIdx.x >> 6);
    if (d >= N) return;
    int lane = threadIdx.x & 63;
    int c0 = lane * 2;

    unsigned xr2 = *(const unsigned*)(xlr + (size_t)d * 256 + 128 + c0);
    float xr0 = lo16(xr2), xr1 = hi16(xr2);
    float2 av = *(const float2*)(att + c0);

    int beg = rowptr[d], end = rowptr[d + 1];
    float den = 0.f, a0 = 0.f, a1 = 0.f;
    int j = beg;
    for (; j + 4 <= end; j += 4) {
        unsigned xv[4];
#pragma unroll
        for (int u = 0; u < 4; u++) {
            int s = esrc[j + u];
            xv[u] = *(const unsigned*)(xlr + (size_t)s * 256 + c0);
        }
#pragma unroll
        for (int u = 0; u < 4; u++) {
            float x0 = lo16(xv[u]), x1 = hi16(xv[u]);
            float v0 = x0 + xr0; v0 = v0 > 0.f ? v0 : NEG_SLOPE * v0;
            float v1 = x1 + xr1; v1 = v1 > 0.f ? v1 : NEG_SLOPE * v1;
            float t = v0 * av.x + v1 * av.y;
            t += __shfl_xor(t, 1);
            t += __shfl_xor(t, 2);
            t += __shfl_xor(t, 4);
            t += __shfl_xor(t, 8);
            float p = __expf(t);
            den += p;
            a0 = fmaf(p, x0, a0);
            a1 = fmaf(p, x1, a1);
        }
    }
    for (; j < end; j++) {
        int s = esrc[j];
        unsigned xv = *(const unsigned*)(xlr + (size_t)s * 256 + c0);
        float x0 = lo16(xv), x1 = hi16(xv);
        float v0 = x0 + xr0; v0 = v0 > 0.f ? v0 : NEG_SLOPE * v0;
        float v1 = x1 + xr1; v1 = v1 > 0.f ? v1 : NEG_SLOPE * v1;
        float t = v0 * av.x + v1 * av.y;
        t += __shfl_xor(t, 1);
        t += __shfl_xor(t, 2);
        t += __shfl_xor(t, 4);
        t += __shfl_xor(t, 8);
        float p = __expf(t);
        den += p;
        a0 = fmaf(p, x0, a0);
        a1 = fmaf(p, x1, a1);
    }

    // fused epilogue: den/acc are complete per lane (every lane saw every edge)
    float inv = 1.f / den;
    float o0 = a0 * inv + bias[c0];
    float o1 = a1 * inv + bias[c0 + 1];
    if (mode == 1) {
        float2 r = *(const float2*)(RES + (size_t)d * 128 + c0);
        o0 += r.x + resB[c0];
        o1 += r.y + resB[c0 + 1];
    } else {
        unsigned hv = *(const unsigned*)(hbf + (size_t)d * 128 + c0);
        o0 += lo16(hv);
        o1 += hi16(hv);
    }
    o0 = (o0 - mm[c0]) * rsqrtf(vv[c0] + BN_EPS) * g[c0] + bb[c0];
    o1 = (o1 - mm[c0 + 1]) * rsqrtf(vv[c0 + 1] + BN_EPS) * g[c0 + 1] + bb[c0 + 1];
    o0 = fmaxf(o0, 0.f);
    o1 = fmaxf(o1, 0.f);
    unsigned w = (unsigned)f2bf(o0) | ((unsigned)f2bf(o1) << 16);
    *(unsigned*)(hbf + (size_t)d * 128 + c0) = w;
}

// ---------------------------------------------------------------------------
// Fused GATv2 agg + epilogue, H=1 C=47 (layer 3). One wave per dst node.
// 16-lane edge groups, unroll-2 (8 edges in flight per wave); lane gl owns
// channels gl*4..+3 (pad channels masked by att=0).
// XLR rows of 128 bf16: xl @0..47(pad), xr @64..111(pad).
// out = BN(agg + b3 + RES + res2_b), no relu.
// ---------------------------------------------------------------------------
__global__ __launch_bounds__(256) void gat_agg1_fused(
    const int* __restrict__ rowptr, const int* __restrict__ esrc,
    const unsigned short* __restrict__ xlr, const float* __restrict__ att,
    const float* __restrict__ RES, const float* __restrict__ resB,
    const float* __restrict__ bias,
    const float* __restrict__ g, const float* __restrict__ bb,
    const float* __restrict__ mm, const float* __restrict__ vv,
    float* __restrict__ out, int N) {
    int d = blockIdx.x * 4 + (threadIdx.x >> 6);
    if (d >= N) return;
    int lane = threadIdx.x & 63;
    int gl = lane & 15, grp = lane >> 4;

    float xr[4], at[4];
    {
        uint2 xv = *(const uint2*)(xlr + (size_t)d * 128 + 64 + gl * 4);
        unpack4(xv, xr);
#pragma unroll
        for (int k = 0; k < 4; k++) {
            int c = gl * 4 + k;
            at[k] = (c < 47) ? att[c] : 0.f;
        }
    }
    int beg = rowptr[d], end = rowptr[d + 1];
    float den = 0.f;
    float acc[4] = {0.f, 0.f, 0.f, 0.f};
    int j = beg + grp;
    for (; j + 4 < end; j += 8) {
        int s0 = esrc[j];
        int s1 = esrc[j + 4];
        uint2 xv0 = *(const uint2*)(xlr + (size_t)s0 * 128 + gl * 4);
        uint2 xv1 = *(const uint2*)(xlr + (size_t)s1 * 128 + gl * 4);
        float xf0[4], xf1[4];
        unpack4(xv0, xf0);
        unpack4(xv1, xf1);
        float t0 = 0.f, t1 = 0.f;
#pragma unroll
        for (int k = 0; k < 4; k++) {
            float v0 = xf0[k] + xr[k];
            v0 = v0 > 0.f ? v0 : NEG_SLOPE * v0;
            t0 = fmaf(v0, at[k], t0);
            float v1 = xf1[k] + xr[k];
            v1 = v1 > 0.f ? v1 : NEG_SLOPE * v1;
            t1 = fmaf(v1, at[k], t1);
        }
        t0 += __shfl_xor(t0, 1);
        t1 += __shfl_xor(t1, 1);
        t0 += __shfl_xor(t0, 2);
        t1 += __shfl_xor(t1, 2);
        t0 += __shfl_xor(t0, 4);
        t1 += __shfl_xor(t1, 4);
        t0 += __shfl_xor(t0, 8);
        t1 += __shfl_xor(t1, 8);
        float p0 = __expf(t0);
        float p1 = __expf(t1);
        den += p0 + p1;
#pragma unroll
        for (int k = 0; k < 4; k++) {
            acc[k] = fmaf(p0, xf0[k], acc[k]);
            acc[k] = fmaf(p1, xf1[k], acc[k]);
        }
    }
    if (j < end) {
        int s = esrc[j];
        uint2 xv = *(const uint2*)(xlr + (size_t)s * 128 + gl * 4);
        float xf[4];
        unpack4(xv, xf);
        float t = 0.f;
#pragma unroll
        for (int k = 0; k < 4; k++) {
            float v = xf[k] + xr[k];
            v = v > 0.f ? v : NEG_SLOPE * v;
            t = fmaf(v, at[k], t);
        }
        t += __shfl_xor(t, 1);
        t += __shfl_xor(t, 2);
        t += __shfl_xor(t, 4);
        t += __shfl_xor(t, 8);
        float p = __expf(t);
        den += p;
#pragma unroll
        for (int k = 0; k < 4; k++) acc[k] = fmaf(p, xf[k], acc[k]);
    }
    den += __shfl_xor(den, 16);
    den += __shfl_xor(den, 32);
#pragma unroll
    for (int k = 0; k < 4; k++) {
        acc[k] += __shfl_xor(acc[k], 16);
        acc[k] += __shfl_xor(acc[k], 32);
    }
    if (grp == 0 && gl < 12) {
        float inv = 1.f / den;
#pragma unroll
        for (int k = 0; k < 4; k++) {
            int c = gl * 4 + k;
            if (c < 47) {
                float o = acc[k] * inv + bias[c] + RES[(size_t)d * 48 + c] + resB[c];
                o = (o - mm[c]) * rsqrtf(vv[c] + BN_EPS) * g[c] + bb[c];
                out[(size_t)d * 47 + c] = o;
            }
        }
    }
}

// ---------------------------------------------------------------------------
extern "C" void kernel_launch(void* const* d_in, const int* in_sizes, int n_in,
                              void* d_out, int out_size, void* d_ws, size_t ws_size,
                              hipStream_t stream) {
    const float* x      = (const float*)d_in[0];
    const int*   ei     = (const int*)d_in[1];
    const float* w1_src = (const float*)d_in[2];
    const float* w1_dst = (const float*)d_in[3];
    const float* att1   = (const float*)d_in[4];
    const float* b1     = (const float*)d_in[5];
    const float* bn1_g  = (const float*)d_in[6];
    const float* bn1_b  = (const float*)d_in[7];
    const float* bn1_m  = (const float*)d_in[8];
    const float* bn1_v  = (const float*)d_in[9];
    const float* res0_w = (const float*)d_in[10];
    const float* res0_b = (const float*)d_in[11];
    const float* w2_src = (const float*)d_in[12];
    const float* w2_dst = (const float*)d_in[13];
    const float* att2   = (const float*)d_in[14];
    const float* b2     = (const float*)d_in[15];
    const float* bn2_g  = (const float*)d_in[16];
    const float* bn2_b  = (const float*)d_in[17];
    const float* bn2_m  = (const float*)d_in[18];
    const float* bn2_v  = (const float*)d_in[19];
    const float* w3_src = (const float*)d_in[20];
    const float* w3_dst = (const float*)d_in[21];
    const float* att3   = (const float*)d_in[22];
    const float* b3     = (const float*)d_in[23];
    const float* bn3_g  = (const float*)d_in[24];
    const float* bn3_b  = (const float*)d_in[25];
    const float* bn3_m  = (const float*)d_in[26];
    const float* bn3_v  = (const float*)d_in[27];
    const float* res2_w = (const float*)d_in[28];
    const float* res2_b = (const float*)d_in[29];

    const int F_IN = 100;
    const int KP = 128;
    const int NC1 = 384, NC2 = 256, NC3 = 144;
    int N = in_sizes[0] / F_IN;
    int E = in_sizes[1] / 2;
    int Etot = E + N;
    const int* src = ei;
    const int* dst = ei + E;

    // ---- workspace layout (float units) ----
    float* ws = (float*)d_ws;
    size_t o = 0;
    unsigned short* XLR = (unsigned short*)(ws + o); o += (size_t)N * 128;  // [N,256] bf16
    float* B_res = ws + o; o += (size_t)N * 128;   // residual cols fp32
    unsigned short* A_bf = (unsigned short*)(ws + o); o += (size_t)N * 64;  // [N,128] bf16
    unsigned short* Wb1  = (unsigned short*)(ws + o); o += (size_t)KP * NC1 / 2;
    unsigned short* Wb2  = (unsigned short*)(ws + o); o += (size_t)KP * NC2 / 2;
    unsigned short* Wb3  = (unsigned short*)(ws + o); o += (size_t)KP * NC3 / 2;
    int* I_deg    = (int*)(ws + o); o += N;
    int* I_cnt    = (int*)(ws + o); o += N;
    int* I_rowptr = (int*)(ws + o); o += N + 4;
    int* I_esrc   = (int*)(ws + o); o += Etot;
    (void)ws_size; (void)n_in; (void)out_size;

    // ---- CSR build ----
    zero_k<<<(N + 255) / 256, 256, 0, stream>>>(I_deg, N);
    hist_k<<<(Etot + 255) / 256, 256, 0, stream>>>(dst, E, Etot, I_deg);
    scan_k<<<1, SCAN_T, 0, stream>>>(I_deg, I_rowptr, I_cnt, N);
    scatter_k<<<(Etot + 255) / 256, 256, 0, stream>>>(src, dst, E, Etot, I_rowptr,
                                                      I_cnt, I_esrc);

    // ---- weight packing (single launch) ----
    {
        int tot = KP * (NC1 + NC2 + NC3);
        pack_all<<<(tot + 255) / 256, 256, 0, stream>>>(
            w1_src, w1_dst, res0_w, w2_src, w2_dst, w3_src, w3_dst, res2_w,
            Wb1, Wb2, Wb3);
    }

    int aggGrid = (N + 3) / 4;
    int mtiles = (N + 15) / 16;

    // ---------------- layer 1 ----------------
    conv_bf<<<(N * KP + 255) / 256, 256, 0, stream>>>(x, A_bf, N, F_IN, KP);
    {
        int waves = mtiles * (NC1 / 64);
        mfma_gemm<4><<<(waves * 64 + 255) / 256, 256, 0, stream>>>(
            A_bf, Wb1, XLR, B_res, N, KP, NC1, 384, 256, 384, 0, 256, 128);
    }
    gat_agg4_fused<<<aggGrid, 256, 0, stream>>>(
        I_rowptr, I_esrc, XLR, att1, B_res, res0_b, b1,
        bn1_g, bn1_b, bn1_m, bn1_v, A_bf, N, 1);

    // ---------------- layer 2 ----------------
    {
        int waves = mtiles * (NC2 / 64);
        mfma_gemm<4><<<(waves * 64 + 255) / 256, 256, 0, stream>>>(
            A_bf, Wb2, XLR, B_res, N, KP, NC2, 256, 256, 256, 0, 256, 128);
    }
    gat_agg4_fused<<<aggGrid, 256, 0, stream>>>(
        I_rowptr, I_esrc, XLR, att2, nullptr, nullptr, b2,
        bn2_g, bn2_b, bn2_m, bn2_v, A_bf, N, 2);

    // ---------------- layer 3 ----------------
    {
        int waves = mtiles * (NC3 / 48);
        mfma_gemm<3><<<(waves * 64 + 255) / 256, 256, 0, stream>>>(
            A_bf, Wb3, XLR, B_res, N, KP, NC3, 141, 94, 47, 17, 128, 48);
    }
    gat_agg1_fused<<<aggGrid, 256, 0, stream>>>(
        I_rowptr, I_esrc, XLR, att3, B_res, res2_b, b3,
        bn3_g, bn3_b, bn3_m, bn3_v, (float*)d_out, N);
}

// Round 7
// 443.238 us; speedup vs baseline: 1.5291x; 1.2486x over previous
//
#include <hip/hip_runtime.h>
#include <math.h>

#define NEG_SLOPE 0.2f
#define BN_EPS 1e-5f

typedef short short8 __attribute__((ext_vector_type(8)));
typedef float float4v __attribute__((ext_vector_type(4)));

// float -> bf16 bits, round-to-nearest-even
static __device__ inline unsigned short f2bf(float f) {
    unsigned u = __float_as_uint(f);
    u = u + 0x7fffu + ((u >> 16) & 1u);
    return (unsigned short)(u >> 16);
}
static __device__ inline float lo16(unsigned v) { return __uint_as_float(v << 16); }
static __device__ inline float hi16(unsigned v) { return __uint_as_float(v & 0xffff0000u); }

static __device__ inline void unpack4(uint2 v, float* f) {
    f[0] = lo16(v.x); f[1] = hi16(v.x);
    f[2] = lo16(v.y); f[3] = hi16(v.y);
}

// ---------------------------------------------------------------------------
// CSR build
// ---------------------------------------------------------------------------
__global__ __launch_bounds__(256) void zero_k(int* __restrict__ p, int n) {
    int i = blockIdx.x * blockDim.x + threadIdx.x;
    if (i < n) p[i] = 0;
}

__global__ __launch_bounds__(256) void hist_k(const int* __restrict__ dst,
                                              int E, int Etot, int* __restrict__ deg) {
    int i = blockIdx.x * blockDim.x + threadIdx.x;
    if (i >= Etot) return;
    int d = (i < E) ? dst[i] : (i - E);
    atomicAdd(&deg[d], 1);
}

// pass 1: per-block (256 elems) reduction of deg -> bsum[bid]
__global__ __launch_bounds__(256) void bred_k(const int* __restrict__ deg,
                                              int* __restrict__ bsum, int N) {
    __shared__ int sh[4];
    int i = blockIdx.x * 256 + threadIdx.x;
    int v = (i < N) ? deg[i] : 0;
    // wave reduce (64 lanes)
    v += __shfl_xor(v, 1);
    v += __shfl_xor(v, 2);
    v += __shfl_xor(v, 4);
    v += __shfl_xor(v, 8);
    v += __shfl_xor(v, 16);
    v += __shfl_xor(v, 32);
    int wid = threadIdx.x >> 6;
    if ((threadIdx.x & 63) == 0) sh[wid] = v;
    __syncthreads();
    if (threadIdx.x == 0) bsum[blockIdx.x] = sh[0] + sh[1] + sh[2] + sh[3];
}

// pass 2: single block scans the block sums (exclusive); writes rowptr[N]=total
__global__ __launch_bounds__(1024) void bscan_k(const int* __restrict__ bsum,
                                                int* __restrict__ bofs, int nb,
                                                int* __restrict__ rowptr, int N) {
    __shared__ int sh[1024];
    int t = threadIdx.x;
    int v = (t < nb) ? bsum[t] : 0;
    sh[t] = v;
    __syncthreads();
    for (int off = 1; off < 1024; off <<= 1) {
        int u = (t >= off) ? sh[t - off] : 0;
        __syncthreads();
        sh[t] += u;
        __syncthreads();
    }
    if (t < nb) bofs[t] = sh[t] - v;
    if (t == 1023) rowptr[N] = sh[1023];
}

// pass 3: per-block exclusive scan of 256 deg values + block offset -> rowptr;
// also zeroes cnt.
__global__ __launch_bounds__(256) void bapply_k(const int* __restrict__ deg,
                                                const int* __restrict__ bofs,
                                                int* __restrict__ rowptr,
                                                int* __restrict__ cnt, int N) {
    __shared__ int sh[256];
    int t = threadIdx.x;
    int i = blockIdx.x * 256 + t;
    int v = (i < N) ? deg[i] : 0;
    sh[t] = v;
    __syncthreads();
    for (int off = 1; off < 256; off <<= 1) {
        int u = (t >= off) ? sh[t - off] : 0;
        __syncthreads();
        sh[t] += u;
        __syncthreads();
    }
    if (i < N) {
        rowptr[i] = bofs[blockIdx.x] + sh[t] - v;
        cnt[i] = 0;
    }
}

__global__ __launch_bounds__(256) void scatter_k(const int* __restrict__ src,
                                                 const int* __restrict__ dst,
                                                 int E, int Etot,
                                                 const int* __restrict__ rowptr,
                                                 int* __restrict__ cnt,
                                                 int* __restrict__ esrc) {
    int i = blockIdx.x * blockDim.x + threadIdx.x;
    if (i >= Etot) return;
    int d = (i < E) ? dst[i] : (i - E);
    int s = (i < E) ? src[i] : (i - E);
    int pos = rowptr[d] + atomicAdd(&cnt[d], 1);
    esrc[pos] = s;
}

// ---------------------------------------------------------------------------
// Weight packing: [p0|p1|p2] -> MFMA B-fragment-major bf16.
// ---------------------------------------------------------------------------
static __device__ inline void pack_one(int idx,
                                       const float* p0, const float* p1,
                                       const float* p2,
                                       int w0, int w1, int w2,
                                       int Ksrc, int Ncat,
                                       unsigned short* out) {
    int k = idx / Ncat, n = idx - k * Ncat;
    float v = 0.f;
    if (k < Ksrc) {
        if (n < w0) v = p0[(size_t)k * w0 + n];
        else if (n < w0 + w1) v = p1[(size_t)k * w1 + (n - w0)];
        else if (w2 > 0 && n < w0 + w1 + w2) v = p2[(size_t)k * w2 + (n - w0 - w1)];
    }
    int kt = k >> 5, kr = k & 31;
    int quad = kr >> 3, j = kr & 7;
    int nt = n >> 4, nr = n & 15;
    int ntiles = Ncat >> 4;
    out[((size_t)(kt * ntiles + nt) * 64 + quad * 16 + nr) * 8 + j] = f2bf(v);
}

__global__ __launch_bounds__(256) void pack_all(const float* __restrict__ w1s,
                                                const float* __restrict__ w1d,
                                                const float* __restrict__ r0w,
                                                const float* __restrict__ w2s,
                                                const float* __restrict__ w2d,
                                                const float* __restrict__ w3s,
                                                const float* __restrict__ w3d,
                                                const float* __restrict__ r2w,
                                                unsigned short* __restrict__ Wb1,
                                                unsigned short* __restrict__ Wb2,
                                                unsigned short* __restrict__ Wb3) {
    const int S1 = 128 * 384, S2 = 128 * 256, S3 = 128 * 144;
    int idx = blockIdx.x * blockDim.x + threadIdx.x;
    if (idx < S1) pack_one(idx, w1s, w1d, r0w, 128, 128, 128, 100, 384, Wb1);
    else if (idx < S1 + S2) pack_one(idx - S1, w2s, w2d, nullptr, 128, 128, 0, 128, 256, Wb2);
    else if (idx < S1 + S2 + S3) pack_one(idx - S1 - S2, w3s, w3d, r2w, 47, 47, 47, 128, 144, Wb3);
}

// convert fp32 [N,Ksrc] -> bf16 [N,Kpad] (zero-padded)
__global__ __launch_bounds__(256) void conv_bf(const float* __restrict__ x,
                                               unsigned short* __restrict__ out,
                                               int N, int Ksrc, int Kpad) {
    int idx = blockIdx.x * blockDim.x + threadIdx.x;
    if (idx >= N * Kpad) return;
    int n = idx / Kpad, k = idx - n * Kpad;
    out[idx] = f2bf(k < Ksrc ? x[(size_t)n * Ksrc + k] : 0.f);
}

// ---------------------------------------------------------------------------
// MFMA bf16 GEMM: one wave = 16 x (16*NT) tile.
// cols < res_off -> bf16 into XLR (col >= bf_remap shifted by +bf_shift);
// cols in [res_off, ncat_valid) -> fp32 into RES; cols >= ncat_valid dropped.
// ---------------------------------------------------------------------------
template <int NT>
__global__ __launch_bounds__(256) void mfma_gemm(const unsigned short* __restrict__ A,
                                                 const unsigned short* __restrict__ Bp,
                                                 unsigned short* __restrict__ XLR,
                                                 float* __restrict__ RES,
                                                 int M, int Kpad, int Ncat,
                                                 int ncat_valid, int res_off,
                                                 int bf_remap, int bf_shift,
                                                 int bf_stride, int res_stride) {
    int wid = (blockIdx.x * blockDim.x + threadIdx.x) >> 6;
    int lane = threadIdx.x & 63;
    int ngroups = Ncat / (16 * NT);
    int mtiles = M >> 4;
    int mt = wid / ngroups;
    int ng = wid - mt * ngroups;
    if (mt >= mtiles) return;
    int quad = lane >> 4;
    int nr = lane & 15;
    int row = mt * 16 + nr;
    int ntiles = Ncat >> 4;

    float4v acc[NT];
#pragma unroll
    for (int t = 0; t < NT; t++) acc[t] = (float4v){0.f, 0.f, 0.f, 0.f};

    for (int k0 = 0; k0 < Kpad; k0 += 32) {
        short8 a = *(const short8*)(A + (size_t)row * Kpad + k0 + quad * 8);
        int kt = k0 >> 5;
        const unsigned short* bbase =
            Bp + ((size_t)(kt * ntiles + ng * NT) * 64 + lane) * 8;
#pragma unroll
        for (int t = 0; t < NT; t++) {
            short8 b = *(const short8*)(bbase + (size_t)t * 64 * 8);
            acc[t] = __builtin_amdgcn_mfma_f32_16x16x32_bf16(a, b, acc[t], 0, 0, 0);
        }
    }
    int rowb = mt * 16 + quad * 4;
#pragma unroll
    for (int t = 0; t < NT; t++) {
        int col = (ng * NT + t) * 16 + nr;
        if (col >= ncat_valid) continue;
        if (col < res_off) {
            int bc = (col >= bf_remap) ? col + bf_shift : col;
#pragma unroll
            for (int r = 0; r < 4; r++)
                XLR[(size_t)(rowb + r) * bf_stride + bc] = f2bf(acc[t][r]);
        } else {
            int rc = col - res_off;
#pragma unroll
            for (int r = 0; r < 4; r++)
                RES[(size_t)(rowb + r) * res_stride + rc] = acc[t][r];
        }
    }
}

// ---------------------------------------------------------------------------
// Fused GATv2 agg + epilogue, H=4 C=32. One wave per dst node; one edge per
// wave-iteration; lane owns channels (2*lane, 2*lane+1); unroll-4.
// XLR rows of 256 bf16: xl @0..127, xr @128..255.
// mode 1: h = relu(BN(agg + bias + RES + resB))      -> hbf (bf16)
// mode 2: h = relu(BN(agg + bias + bf16(hbf_prev)))  -> hbf in-place
// ---------------------------------------------------------------------------
__global__ __launch_bounds__(256) void gat_agg4_fused(
    const int* __restrict__ rowptr, const int* __restrict__ esrc,
    const unsigned short* __restrict__ xlr, const float* __restrict__ att,
    const float* __restrict__ RES, const float* __restrict__ resB,
    const float* __restrict__ bias,
    const float* __restrict__ g, const float* __restrict__ bb,
    const float* __restrict__ mm, const float* __restrict__ vv,
    unsigned short* __restrict__ hbf, int N, int mode) {
    int d = blockIdx.x * 4 + (threadIdx.x >> 6);
    if (d >= N) return;
    int lane = threadIdx.x & 63;
    int c0 = lane * 2;

    unsigned xr2 = *(const unsigned*)(xlr + (size_t)d * 256 + 128 + c0);
    float xr0 = lo16(xr2), xr1 = hi16(xr2);
    float2 av = *(const float2*)(att + c0);

    int beg = rowptr[d], end = rowptr[d + 1];
    float den = 0.f, a0 = 0.f, a1 = 0.f;
    int j = beg;
    for (; j + 4 <= end; j += 4) {
        unsigned xv[4];
#pragma unroll
        for (int u = 0; u < 4; u++) {
            int s = esrc[j + u];
            xv[u] = *(const unsigned*)(xlr + (size_t)s * 256 + c0);
        }
#pragma unroll
        for (int u = 0; u < 4; u++) {
            float x0 = lo16(xv[u]), x1 = hi16(xv[u]);
            float v0 = x0 + xr0; v0 = v0 > 0.f ? v0 : NEG_SLOPE * v0;
            float v1 = x1 + xr1; v1 = v1 > 0.f ? v1 : NEG_SLOPE * v1;
            float t = v0 * av.x + v1 * av.y;
            t += __shfl_xor(t, 1);
            t += __shfl_xor(t, 2);
            t += __shfl_xor(t, 4);
            t += __shfl_xor(t, 8);
            float p = __expf(t);
            den += p;
            a0 = fmaf(p, x0, a0);
            a1 = fmaf(p, x1, a1);
        }
    }
    for (; j < end; j++) {
        int s = esrc[j];
        unsigned xv = *(const unsigned*)(xlr + (size_t)s * 256 + c0);
        float x0 = lo16(xv), x1 = hi16(xv);
        float v0 = x0 + xr0; v0 = v0 > 0.f ? v0 : NEG_SLOPE * v0;
        float v1 = x1 + xr1; v1 = v1 > 0.f ? v1 : NEG_SLOPE * v1;
        float t = v0 * av.x + v1 * av.y;
        t += __shfl_xor(t, 1);
        t += __shfl_xor(t, 2);
        t += __shfl_xor(t, 4);
        t += __shfl_xor(t, 8);
        float p = __expf(t);
        den += p;
        a0 = fmaf(p, x0, a0);
        a1 = fmaf(p, x1, a1);
    }

    // fused epilogue: den/acc are complete per lane (every lane saw every edge)
    float inv = 1.f / den;
    float o0 = a0 * inv + bias[c0];
    float o1 = a1 * inv + bias[c0 + 1];
    if (mode == 1) {
        float2 r = *(const float2*)(RES + (size_t)d * 128 + c0);
        o0 += r.x + resB[c0];
        o1 += r.y + resB[c0 + 1];
    } else {
        unsigned hv = *(const unsigned*)(hbf + (size_t)d * 128 + c0);
        o0 += lo16(hv);
        o1 += hi16(hv);
    }
    o0 = (o0 - mm[c0]) * rsqrtf(vv[c0] + BN_EPS) * g[c0] + bb[c0];
    o1 = (o1 - mm[c0 + 1]) * rsqrtf(vv[c0 + 1] + BN_EPS) * g[c0 + 1] + bb[c0 + 1];
    o0 = fmaxf(o0, 0.f);
    o1 = fmaxf(o1, 0.f);
    unsigned w = (unsigned)f2bf(o0) | ((unsigned)f2bf(o1) << 16);
    *(unsigned*)(hbf + (size_t)d * 128 + c0) = w;
}

// ---------------------------------------------------------------------------
// Fused GATv2 agg + epilogue, H=1 C=47 (layer 3). One wave per dst node.
// 16-lane edge groups, unroll-2; lane gl owns channels gl*4..+3.
// XLR rows of 128 bf16: xl @0..47(pad), xr @64..111(pad).
// out = BN(agg + b3 + RES + res2_b), no relu.
// ---------------------------------------------------------------------------
__global__ __launch_bounds__(256) void gat_agg1_fused(
    const int* __restrict__ rowptr, const int* __restrict__ esrc,
    const unsigned short* __restrict__ xlr, const float* __restrict__ att,
    const float* __restrict__ RES, const float* __restrict__ resB,
    const float* __restrict__ bias,
    const float* __restrict__ g, const float* __restrict__ bb,
    const float* __restrict__ mm, const float* __restrict__ vv,
    float* __restrict__ out, int N) {
    int d = blockIdx.x * 4 + (threadIdx.x >> 6);
    if (d >= N) return;
    int lane = threadIdx.x & 63;
    int gl = lane & 15, grp = lane >> 4;

    float xr[4], at[4];
    {
        uint2 xv = *(const uint2*)(xlr + (size_t)d * 128 + 64 + gl * 4);
        unpack4(xv, xr);
#pragma unroll
        for (int k = 0; k < 4; k++) {
            int c = gl * 4 + k;
            at[k] = (c < 47) ? att[c] : 0.f;
        }
    }
    int beg = rowptr[d], end = rowptr[d + 1];
    float den = 0.f;
    float acc[4] = {0.f, 0.f, 0.f, 0.f};
    int j = beg + grp;
    for (; j + 4 < end; j += 8) {
        int s0 = esrc[j];
        int s1 = esrc[j + 4];
        uint2 xv0 = *(const uint2*)(xlr + (size_t)s0 * 128 + gl * 4);
        uint2 xv1 = *(const uint2*)(xlr + (size_t)s1 * 128 + gl * 4);
        float xf0[4], xf1[4];
        unpack4(xv0, xf0);
        unpack4(xv1, xf1);
        float t0 = 0.f, t1 = 0.f;
#pragma unroll
        for (int k = 0; k < 4; k++) {
            float v0 = xf0[k] + xr[k];
            v0 = v0 > 0.f ? v0 : NEG_SLOPE * v0;
            t0 = fmaf(v0, at[k], t0);
            float v1 = xf1[k] + xr[k];
            v1 = v1 > 0.f ? v1 : NEG_SLOPE * v1;
            t1 = fmaf(v1, at[k], t1);
        }
        t0 += __shfl_xor(t0, 1);
        t1 += __shfl_xor(t1, 1);
        t0 += __shfl_xor(t0, 2);
        t1 += __shfl_xor(t1, 2);
        t0 += __shfl_xor(t0, 4);
        t1 += __shfl_xor(t1, 4);
        t0 += __shfl_xor(t0, 8);
        t1 += __shfl_xor(t1, 8);
        float p0 = __expf(t0);
        float p1 = __expf(t1);
        den += p0 + p1;
#pragma unroll
        for (int k = 0; k < 4; k++) {
            acc[k] = fmaf(p0, xf0[k], acc[k]);
            acc[k] = fmaf(p1, xf1[k], acc[k]);
        }
    }
    if (j < end) {
        int s = esrc[j];
        uint2 xv = *(const uint2*)(xlr + (size_t)s * 128 + gl * 4);
        float xf[4];
        unpack4(xv, xf);
        float t = 0.f;
#pragma unroll
        for (int k = 0; k < 4; k++) {
            float v = xf[k] + xr[k];
            v = v > 0.f ? v : NEG_SLOPE * v;
            t = fmaf(v, at[k], t);
        }
        t += __shfl_xor(t, 1);
        t += __shfl_xor(t, 2);
        t += __shfl_xor(t, 4);
        t += __shfl_xor(t, 8);
        float p = __expf(t);
        den += p;
#pragma unroll
        for (int k = 0; k < 4; k++) acc[k] = fmaf(p, xf[k], acc[k]);
    }
    den += __shfl_xor(den, 16);
    den += __shfl_xor(den, 32);
#pragma unroll
    for (int k = 0; k < 4; k++) {
        acc[k] += __shfl_xor(acc[k], 16);
        acc[k] += __shfl_xor(acc[k], 32);
    }
    if (grp == 0 && gl < 12) {
        float inv = 1.f / den;
#pragma unroll
        for (int k = 0; k < 4; k++) {
            int c = gl * 4 + k;
            if (c < 47) {
                float o = acc[k] * inv + bias[c] + RES[(size_t)d * 48 + c] + resB[c];
                o = (o - mm[c]) * rsqrtf(vv[c] + BN_EPS) * g[c] + bb[c];
                out[(size_t)d * 47 + c] = o;
            }
        }
    }
}

// ---------------------------------------------------------------------------
extern "C" void kernel_launch(void* const* d_in, const int* in_sizes, int n_in,
                              void* d_out, int out_size, void* d_ws, size_t ws_size,
                              hipStream_t stream) {
    const float* x      = (const float*)d_in[0];
    const int*   ei     = (const int*)d_in[1];
    const float* w1_src = (const float*)d_in[2];
    const float* w1_dst = (const float*)d_in[3];
    const float* att1   = (const float*)d_in[4];
    const float* b1     = (const float*)d_in[5];
    const float* bn1_g  = (const float*)d_in[6];
    const float* bn1_b  = (const float*)d_in[7];
    const float* bn1_m  = (const float*)d_in[8];
    const float* bn1_v  = (const float*)d_in[9];
    const float* res0_w = (const float*)d_in[10];
    const float* res0_b = (const float*)d_in[11];
    const float* w2_src = (const float*)d_in[12];
    const float* w2_dst = (const float*)d_in[13];
    const float* att2   = (const float*)d_in[14];
    const float* b2     = (const float*)d_in[15];
    const float* bn2_g  = (const float*)d_in[16];
    const float* bn2_b  = (const float*)d_in[17];
    const float* bn2_m  = (const float*)d_in[18];
    const float* bn2_v  = (const float*)d_in[19];
    const float* w3_src = (const float*)d_in[20];
    const float* w3_dst = (const float*)d_in[21];
    const float* att3   = (const float*)d_in[22];
    const float* b3     = (const float*)d_in[23];
    const float* bn3_g  = (const float*)d_in[24];
    const float* bn3_b  = (const float*)d_in[25];
    const float* bn3_m  = (const float*)d_in[26];
    const float* bn3_v  = (const float*)d_in[27];
    const float* res2_w = (const float*)d_in[28];
    const float* res2_b = (const float*)d_in[29];

    const int F_IN = 100;
    const int KP = 128;
    const int NC1 = 384, NC2 = 256, NC3 = 144;
    int N = in_sizes[0] / F_IN;
    int E = in_sizes[1] / 2;
    int Etot = E + N;
    const int* src = ei;
    const int* dst = ei + E;
    int nb = (N + 255) / 256;

    // ---- workspace layout (float units) ----
    float* ws = (float*)d_ws;
    size_t o = 0;
    unsigned short* XLR = (unsigned short*)(ws + o); o += (size_t)N * 128;  // [N,256] bf16
    float* B_res = ws + o; o += (size_t)N * 128;   // residual cols fp32
    unsigned short* A_bf = (unsigned short*)(ws + o); o += (size_t)N * 64;  // [N,128] bf16
    unsigned short* Wb1  = (unsigned short*)(ws + o); o += (size_t)KP * NC1 / 2;
    unsigned short* Wb2  = (unsigned short*)(ws + o); o += (size_t)KP * NC2 / 2;
    unsigned short* Wb3  = (unsigned short*)(ws + o); o += (size_t)KP * NC3 / 2;
    int* I_deg    = (int*)(ws + o); o += N;
    int* I_cnt    = (int*)(ws + o); o += N;
    int* I_rowptr = (int*)(ws + o); o += N + 4;
    int* I_bsum   = (int*)(ws + o); o += nb + 4;
    int* I_bofs   = (int*)(ws + o); o += nb + 4;
    int* I_esrc   = (int*)(ws + o); o += Etot;
    (void)ws_size; (void)n_in; (void)out_size;

    // ---- CSR build (parallel scan) ----
    zero_k<<<(N + 255) / 256, 256, 0, stream>>>(I_deg, N);
    hist_k<<<(Etot + 255) / 256, 256, 0, stream>>>(dst, E, Etot, I_deg);
    bred_k<<<nb, 256, 0, stream>>>(I_deg, I_bsum, N);
    bscan_k<<<1, 1024, 0, stream>>>(I_bsum, I_bofs, nb, I_rowptr, N);
    bapply_k<<<nb, 256, 0, stream>>>(I_deg, I_bofs, I_rowptr, I_cnt, N);
    scatter_k<<<(Etot + 255) / 256, 256, 0, stream>>>(src, dst, E, Etot, I_rowptr,
                                                      I_cnt, I_esrc);

    // ---- weight packing (single launch) ----
    {
        int tot = KP * (NC1 + NC2 + NC3);
        pack_all<<<(tot + 255) / 256, 256, 0, stream>>>(
            w1_src, w1_dst, res0_w, w2_src, w2_dst, w3_src, w3_dst, res2_w,
            Wb1, Wb2, Wb3);
    }

    int aggGrid = (N + 3) / 4;
    int mtiles = (N + 15) / 16;

    // ---------------- layer 1 ----------------
    conv_bf<<<(N * KP + 255) / 256, 256, 0, stream>>>(x, A_bf, N, F_IN, KP);
    {
        int waves = mtiles * (NC1 / 64);
        mfma_gemm<4><<<(waves * 64 + 255) / 256, 256, 0, stream>>>(
            A_bf, Wb1, XLR, B_res, N, KP, NC1, 384, 256, 384, 0, 256, 128);
    }
    gat_agg4_fused<<<aggGrid, 256, 0, stream>>>(
        I_rowptr, I_esrc, XLR, att1, B_res, res0_b, b1,
        bn1_g, bn1_b, bn1_m, bn1_v, A_bf, N, 1);

    // ---------------- layer 2 ----------------
    {
        int waves = mtiles * (NC2 / 64);
        mfma_gemm<4><<<(waves * 64 + 255) / 256, 256, 0, stream>>>(
            A_bf, Wb2, XLR, B_res, N, KP, NC2, 256, 256, 256, 0, 256, 128);
    }
    gat_agg4_fused<<<aggGrid, 256, 0, stream>>>(
        I_rowptr, I_esrc, XLR, att2, nullptr, nullptr, b2,
        bn2_g, bn2_b, bn2_m, bn2_v, A_bf, N, 2);

    // ---------------- layer 3 ----------------
    {
        int waves = mtiles * (NC3 / 48);
        mfma_gemm<3><<<(waves * 64 + 255) / 256, 256, 0, stream>>>(
            A_bf, Wb3, XLR, B_res, N, KP, NC3, 141, 94, 47, 17, 128, 48);
    }
    gat_agg1_fused<<<aggGrid, 256, 0, stream>>>(
        I_rowptr, I_esrc, XLR, att3, B_res, res2_b, b3,
        bn3_g, bn3_b, bn3_m, bn3_v, (float*)d_out, N);
}